// Round 8
// baseline (111.517 us; speedup 1.0000x reference)
//
#include <hip/hip_runtime.h>
#include <math.h>

#define H_DIM 4096
#define I_DIM 14336
#define HB_DIM 1024
#define SC_K 4300
#define HC_K 716

__device__ __forceinline__ unsigned sortable(float f) {
    unsigned u = __float_as_uint(f);
    return (u & 0x80000000u) ? ~u : (u | 0x80000000u);
}

// dot(x, gate_w[row]) & dot(x, up_w[row]) by one wave; tv[row] = silu(g)*u
__device__ __forceinline__ void compute_tv_row(const float* __restrict__ x,
                                               const float* __restrict__ gate_w,
                                               const float* __restrict__ up_w,
                                               float* __restrict__ tv, int row, int lane) {
    const float* gr = gate_w + (size_t)row * H_DIM;
    const float* ur = up_w + (size_t)row * H_DIM;
    float gs = 0.f, us = 0.f;
#pragma unroll 4
    for (int c = 0; c < H_DIM; c += 256) {
        int cc = c + lane * 4;
        float4 xv = *(const float4*)(x + cc);
        float4 g = *(const float4*)(gr + cc);
        float4 u = *(const float4*)(ur + cc);
        gs += g.x * xv.x + g.y * xv.y + g.z * xv.z + g.w * xv.w;
        us += u.x * xv.x + u.y * xv.y + u.z * xv.z + u.w * xv.w;
    }
#pragma unroll
    for (int o = 32; o >= 1; o >>= 1) {
        gs += __shfl_xor(gs, o);
        us += __shfl_xor(us, o);
    }
    if (lane == 0) {
        float s = gs / (1.f + expf(-gs));
        tv[row] = s * us;
    }
}

// K1: blocks [0,256): h1 = x @ hw1^T (wave per row).
//     blocks [256,1331): gate/up for ALL x_topk entries — duplicates write
//     bitwise-identical tv values (benign race), so no dedup/atomics needed.
__global__ __launch_bounds__(256) void k1_h1_gateup(
    const float* __restrict__ x, const float* __restrict__ hw1,
    const int* __restrict__ x_topk, const float* __restrict__ gate_w,
    const float* __restrict__ up_w, float* __restrict__ h1,
    float* __restrict__ tv) {
    int wid = threadIdx.x >> 6, lane = threadIdx.x & 63;
    int b = blockIdx.x;
    if (b < 256) {
        int row = b * 4 + wid;  // 0..1023
        const float* mr = hw1 + (size_t)row * H_DIM;
        float s = 0.f;
#pragma unroll 4
        for (int c = 0; c < H_DIM; c += 256) {
            int cc = c + lane * 4;
            float4 m = *(const float4*)(mr + cc);
            float4 v = *(const float4*)(x + cc);
            s += m.x * v.x + m.y * v.y + m.z * v.z + m.w * v.w;
        }
#pragma unroll
        for (int o = 32; o >= 1; o >>= 1) s += __shfl_xor(s, o);
        if (lane == 0) h1[row] = s;
    } else {
        int gw = (b - 256) * 4 + wid;  // 0..4299 (grid sized exactly)
        if (gw < SC_K) {
            int idx = x_topk[gw];
            if ((unsigned)idx < (unsigned)I_DIM)
                compute_tv_row(x, gate_w, up_w, tv, idx, lane);
        }
    }
}

// K2: h = h1 @ hw2^T (wave per row).
__global__ __launch_bounds__(256) void k2_h(
    const float* __restrict__ h1, const float* __restrict__ hw2,
    float* __restrict__ hbuf) {
    int wid = threadIdx.x >> 6, lane = threadIdx.x & 63;
    int row = blockIdx.x * 4 + wid;
    const float* mr = hw2 + (size_t)row * HB_DIM;
    float s = 0.f;
#pragma unroll
    for (int c = 0; c < HB_DIM; c += 256) {
        int cc = c + lane * 4;
        float4 m = *(const float4*)(mr + cc);
        float4 v = *(const float4*)(h1 + cc);
        s += m.x * v.x + m.y * v.y + m.z * v.z + m.w * v.w;
    }
#pragma unroll
    for (int o = 32; o >= 1; o >>= 1) s += __shfl_xor(s, o);
    if (lane == 0) hbuf[row] = s;
}

// K3': 256 blocks × 1024 threads. EVERY block redundantly computes the
// identical radix-select of top HC_K of h (keys in registers, LDS histogram —
// per-CU, fully parallel, no inter-block traffic). Tie-break toward lowest
// index (stable jax.lax.top_k). Then each block finishes its own 56-row
// slice: tv=0 for untouched rows, gate/up for selected-&&-!topk rows.
__global__ __launch_bounds__(1024) void k3_select_residual(
    const float* __restrict__ h, const int* __restrict__ x_topk,
    const float* __restrict__ x, const float* __restrict__ gate_w,
    const float* __restrict__ up_w, float* __restrict__ tv) {
    __shared__ unsigned bins[2048];
    __shared__ unsigned wpart[16];
    __shared__ unsigned bitT[448], bitS[448];  // 14336 bits each
    __shared__ int s_b, s_above, s_tie_cnt;
    __shared__ int tie_idx[2048];
    int tid = threadIdx.x;
    int lane = tid & 63, wid = tid >> 6;

    unsigned key[14];
#pragma unroll
    for (int j = 0; j < 14; ++j) key[j] = sortable(h[j * 1024 + tid]);

    if (tid < 448) { bitT[tid] = 0; bitS[tid] = 0; }
    if (tid == 0) s_tie_cnt = 0;
    __syncthreads();

    // x_topk membership bitmap
    for (int k = tid; k < SC_K; k += 1024) {
        int idx = x_topk[k];
        if ((unsigned)idx < (unsigned)I_DIM) atomicOr(&bitT[idx >> 5], 1u << (idx & 31));
    }

    int b1 = 0, b2 = 0;
    int above = 0;
    unsigned T = 0;
    int need2 = 0;

    for (int pass = 0; pass < 3; ++pass) {
        int nb = (pass == 2) ? 1024 : 2048;
        bins[tid] = 0;
        if (nb == 2048) bins[tid + 1024] = 0;
        __syncthreads();
#pragma unroll
        for (int j = 0; j < 14; ++j) {
            unsigned u = key[j];
            bool in_sub = (pass == 0) ||
                          ((pass == 1) ? ((int)(u >> 21) == b1)
                                       : ((int)(u >> 21) == b1 && (int)((u >> 10) & 0x7FF) == b2));
            if (in_sub) {
                unsigned k = (pass == 0) ? (u >> 21)
                           : (pass == 1) ? ((u >> 10) & 0x7FF)
                                         : (u & 0x3FF);
                atomicAdd(&bins[k], 1u);
            }
        }
        __syncthreads();
        // thread t owns bins[2t], bins[2t+1] (zero beyond nb)
        unsigned c0 = (2 * tid < nb) ? bins[2 * tid] : 0u;
        unsigned c1 = (2 * tid + 1 < nb) ? bins[2 * tid + 1] : 0u;
        unsigned s = c0 + c1;
        unsigned incl = s;
#pragma unroll
        for (int o = 1; o < 64; o <<= 1) {
            unsigned v = __shfl_up(incl, o);
            if (lane >= o) incl += v;
        }
        if (lane == 63) wpart[wid] = incl;
        __syncthreads();
        if (wid == 0 && lane < 16) {
            unsigned p = wpart[lane];
#pragma unroll
            for (int o = 1; o < 16; o <<= 1) {
                unsigned v = __shfl_up(p, o, 16);
                if (lane >= o) p += v;
            }
            wpart[lane] = p;
        }
        __syncthreads();
        unsigned total = wpart[15];
        unsigned base = (wid > 0 ? wpart[wid - 1] : 0u) + (incl - s);
        unsigned need = (unsigned)(HC_K - above);
        if (2 * tid < nb) {
            unsigned Pm1 = base, P = base + c0;
            if (total - P < need && total - Pm1 >= need) { s_b = 2 * tid; s_above = above + (int)(total - P); }
        }
        if (2 * tid + 1 < nb) {
            unsigned Pm1 = base + c0, P = base + c0 + c1;
            if (total - P < need && total - Pm1 >= need) { s_b = 2 * tid + 1; s_above = above + (int)(total - P); }
        }
        __syncthreads();
        if (pass == 0) b1 = s_b;
        else if (pass == 1) b2 = s_b;
        above = s_above;
        if (pass == 2) {
            T = ((unsigned)b1 << 21) | ((unsigned)b2 << 10) | (unsigned)s_b;
            need2 = HC_K - above;
        }
        __syncthreads();
    }

    // mark selected rows in bitS: strictly-above + lowest-index ties
#pragma unroll
    for (int j = 0; j < 14; ++j) {
        unsigned u = key[j];
        int i = j * 1024 + tid;
        if (u > T) atomicOr(&bitS[i >> 5], 1u << (i & 31));
        else if (u == T) {
            int p = atomicAdd(&s_tie_cnt, 1);
            if (p < 2048) tie_idx[p] = i;
        }
    }
    __syncthreads();
    int C = s_tie_cnt;
    if (C <= 2048) {
        for (int m = tid; m < C; m += 1024) {
            int my = tie_idx[m];
            int rank = 0;
            for (int j = 0; j < C; ++j) rank += (tie_idx[j] < my) ? 1 : 0;
            if (rank < need2) atomicOr(&bitS[my >> 5], 1u << (my & 31));
        }
    } else if (tid == 0) {  // degenerate mass-tie fallback (never expected)
        int left = need2;
        for (int i = 0; i < I_DIM && left > 0; ++i)
            if (sortable(h[i]) == T) { atomicOr(&bitS[i >> 5], 1u << (i & 31)); --left; }
    }
    __syncthreads();

    // ---- this block's 56-row slice: zero untouched rows, gate/up residuals
    int base_row = blockIdx.x * 56;
    // phase A: thread-per-row zeroing (rows neither topk nor selected)
    for (int r = tid; r < 56; r += 1024) {
        int i = base_row + r;
        bool t = (bitT[i >> 5] >> (i & 31)) & 1u;
        bool sl = (bitS[i >> 5] >> (i & 31)) & 1u;
        if (!t && !sl) tv[i] = 0.f;
    }
    // phase B: wave-per-row gate/up for selected && !topk
    for (int r = wid; r < 56; r += 16) {
        int i = base_row + r;
        bool t = (bitT[i >> 5] >> (i & 31)) & 1u;
        bool sl = (bitS[i >> 5] >> (i & 31)) & 1u;
        if (sl && !t) compute_tv_row(x, gate_w, up_w, tv, i, lane);
    }
}

// K4: out = down_w @ tv (wave per output row, dense over I).
__global__ __launch_bounds__(256) void k4_down(
    const float* __restrict__ tv, const float* __restrict__ down_w,
    float* __restrict__ out) {
    int wid = threadIdx.x >> 6, lane = threadIdx.x & 63;
    int row = blockIdx.x * 4 + wid;  // 0..4095
    const float* mr = down_w + (size_t)row * I_DIM;
    float s = 0.f;
#pragma unroll 4
    for (int c = 0; c < I_DIM; c += 256) {
        int cc = c + lane * 4;
        float4 m = *(const float4*)(mr + cc);
        float4 v = *(const float4*)(tv + cc);
        s += m.x * v.x + m.y * v.y + m.z * v.z + m.w * v.w;
    }
#pragma unroll
    for (int o = 32; o >= 1; o >>= 1) s += __shfl_xor(s, o);
    if (lane == 0) out[row] = s;
}

extern "C" void kernel_launch(void* const* d_in, const int* in_sizes, int n_in,
                              void* d_out, int out_size, void* d_ws, size_t ws_size,
                              hipStream_t stream) {
    const float* x      = (const float*)d_in[0];
    const int*   x_topk = (const int*)d_in[1];
    const float* gate_w = (const float*)d_in[2];
    const float* up_w   = (const float*)d_in[3];
    const float* down_w = (const float*)d_in[4];
    const float* hw1    = (const float*)d_in[5];
    const float* hw2    = (const float*)d_in[6];
    float* out = (float*)d_out;

    float* ws   = (float*)d_ws;
    float* h1   = ws;                    // 1024
    float* hbuf = ws + 1024;             // 14336
    float* tv   = ws + 1024 + I_DIM;     // 14336

    // K1: h1 GEMV (256 blocks) || gate/up for all x_topk entries (1075 blocks)
    k1_h1_gateup<<<256 + (SC_K + 3) / 4, 256, 0, stream>>>(x, hw1, x_topk, gate_w,
                                                           up_w, h1, tv);
    // K2: h GEMV
    k2_h<<<I_DIM / 4, 256, 0, stream>>>(h1, hw2, hbuf);
    // K3': redundant select per block + residual gate/up + zeroing (256 blocks)
    k3_select_residual<<<256, 1024, 0, stream>>>(hbuf, x_topk, x, gate_w, up_w, tv);
    // K4: dense down-projection
    k4_down<<<H_DIM / 4, 256, 0, stream>>>(tv, down_w, out);
}

// Round 10
// 99.940 us; speedup vs baseline: 1.1158x; 1.1158x over previous
//
#include <hip/hip_runtime.h>
#include <math.h>

#define H_DIM 4096
#define I_DIM 14336
#define HB_DIM 1024
#define SC_K 4300
#define HC_K 716

typedef float floatx4 __attribute__((ext_vector_type(4)));

__device__ __forceinline__ unsigned sortable(float f) {
    unsigned u = __float_as_uint(f);
    return (u & 0x80000000u) ? ~u : (u | 0x80000000u);
}

__device__ __forceinline__ floatx4 ntload4(const float* p) {
    return __builtin_nontemporal_load((const floatx4*)p);
}

// dot(x, gate_w[row]) & dot(x, up_w[row]) by one wave; tv[row] = silu(g)*u
__device__ __forceinline__ void compute_tv_row(const float* __restrict__ x,
                                               const float* __restrict__ gate_w,
                                               const float* __restrict__ up_w,
                                               float* __restrict__ tv, int row, int lane) {
    const float* gr = gate_w + (size_t)row * H_DIM;
    const float* ur = up_w + (size_t)row * H_DIM;
    float gs = 0.f, us = 0.f;
#pragma unroll 4
    for (int c = 0; c < H_DIM; c += 256) {
        int cc = c + lane * 4;
        float4 xv = *(const float4*)(x + cc);
        floatx4 g = ntload4(gr + cc);
        floatx4 u = ntload4(ur + cc);
        gs += g.x * xv.x + g.y * xv.y + g.z * xv.z + g.w * xv.w;
        us += u.x * xv.x + u.y * xv.y + u.z * xv.z + u.w * xv.w;
    }
#pragma unroll
    for (int o = 32; o >= 1; o >>= 1) {
        gs += __shfl_xor(gs, o);
        us += __shfl_xor(us, o);
    }
    if (lane == 0) {
        float s = gs / (1.f + expf(-gs));
        tv[row] = s * us;
    }
}

// K1: blocks [0,256): h1 = x @ hw1^T (wave per row, nt weight stream).
//     blocks [256,1331): gate/up for ALL x_topk entries — duplicates write
//     bitwise-identical tv values (benign race), so no dedup/atomics needed.
__global__ __launch_bounds__(256) void k1_h1_gateup(
    const float* __restrict__ x, const float* __restrict__ hw1,
    const int* __restrict__ x_topk, const float* __restrict__ gate_w,
    const float* __restrict__ up_w, float* __restrict__ h1,
    float* __restrict__ tv) {
    int wid = threadIdx.x >> 6, lane = threadIdx.x & 63;
    int b = blockIdx.x;
    if (b < 256) {
        int row = b * 4 + wid;  // 0..1023
        const float* mr = hw1 + (size_t)row * H_DIM;
        float s = 0.f;
#pragma unroll 4
        for (int c = 0; c < H_DIM; c += 256) {
            int cc = c + lane * 4;
            floatx4 m = ntload4(mr + cc);
            float4 v = *(const float4*)(x + cc);
            s += m.x * v.x + m.y * v.y + m.z * v.z + m.w * v.w;
        }
#pragma unroll
        for (int o = 32; o >= 1; o >>= 1) s += __shfl_xor(s, o);
        if (lane == 0) h1[row] = s;
    } else {
        int gw = (b - 256) * 4 + wid;  // 0..4299 (grid sized exactly)
        if (gw < SC_K) {
            int idx = x_topk[gw];
            if ((unsigned)idx < (unsigned)I_DIM)
                compute_tv_row(x, gate_w, up_w, tv, idx, lane);
        }
    }
}

// K2: h = h1 @ hw2^T (wave per row, nt weight stream).
__global__ __launch_bounds__(256) void k2_h(
    const float* __restrict__ h1, const float* __restrict__ hw2,
    float* __restrict__ hbuf) {
    int wid = threadIdx.x >> 6, lane = threadIdx.x & 63;
    int row = blockIdx.x * 4 + wid;
    const float* mr = hw2 + (size_t)row * HB_DIM;
    float s = 0.f;
#pragma unroll
    for (int c = 0; c < HB_DIM; c += 256) {
        int cc = c + lane * 4;
        floatx4 m = ntload4(mr + cc);
        float4 v = *(const float4*)(h1 + cc);
        s += m.x * v.x + m.y * v.y + m.z * v.z + m.w * v.w;
    }
#pragma unroll
    for (int o = 32; o >= 1; o >>= 1) s += __shfl_xor(s, o);
    if (lane == 0) hbuf[row] = s;
}

// Single-block (1024-thread) radix-select of top HC_K of h.
// 4 passes x 8-bit digits with PER-WAVE histograms (hist[16][256]) — removes
// cross-wave same-address LDS-atomic serialization that made the 11-bit
// version slow on exponent-skewed keys. Tie-break toward lowest index
// (stable jax.lax.top_k). Emits tv zeros for untouched rows + compact
// residual list (selected && !topk) + count.
__global__ __launch_bounds__(1024) void select_kernel(
    const float* __restrict__ h, const int* __restrict__ x_topk,
    float* __restrict__ tv, int* __restrict__ rlist, int* __restrict__ rcount) {
    __shared__ unsigned hist[16][256];
    __shared__ unsigned wpart[4];
    __shared__ unsigned bitT[448], bitS[448];  // 14336 bits each
    __shared__ int s_d, s_above, s_tie_cnt, s_rc;
    __shared__ int tie_idx[2048];
    int tid = threadIdx.x;
    int lane = tid & 63, wid = tid >> 6;

    unsigned key[14];
#pragma unroll
    for (int j = 0; j < 14; ++j) key[j] = sortable(h[j * 1024 + tid]);

    if (tid < 448) { bitT[tid] = 0; bitS[tid] = 0; }
    if (tid == 0) { s_tie_cnt = 0; s_rc = 0; }
    __syncthreads();

    // x_topk membership bitmap
    for (int k = tid; k < SC_K; k += 1024) {
        int idx = x_topk[k];
        if ((unsigned)idx < (unsigned)I_DIM) atomicOr(&bitT[idx >> 5], 1u << (idx & 31));
    }

    unsigned prefix = 0;
    int above = 0;  // # keys strictly greater than current prefix-extension

    for (int p = 0; p < 4; ++p) {
        int s = 24 - 8 * p;
        // zero per-wave histograms (16*256 = 4096 words)
        {
            unsigned* hp = &hist[0][0];
            for (int i = tid; i < 4096; i += 1024) hp[i] = 0;
        }
        __syncthreads();
#pragma unroll
        for (int j = 0; j < 14; ++j) {
            unsigned u = key[j];
            bool in_sub = (p == 0) || ((u >> (s + 8)) == (prefix >> (s + 8)));
            if (in_sub) atomicAdd(&hist[wid][(u >> s) & 0xFF], 1u);
        }
        __syncthreads();
        // reduce 16 copies + inclusive scan over 256 bins (waves 0..3)
        unsigned cnt = 0, incl = 0;
        if (tid < 256) {
#pragma unroll
            for (int w = 0; w < 16; ++w) cnt += hist[w][tid];
        }
        incl = cnt;
#pragma unroll
        for (int o = 1; o < 64; o <<= 1) {
            unsigned v = __shfl_up(incl, o);
            if (lane >= o) incl += v;
        }
        if (tid < 256 && lane == 63) wpart[wid] = incl;
        __syncthreads();
        if (tid < 256) {
            unsigned add = 0;
            for (int w2 = 0; w2 < wid; ++w2) add += wpart[w2];
            incl += add;
            unsigned total = wpart[0] + wpart[1] + wpart[2] + wpart[3];
            unsigned suf = total - incl;  // # in-subset keys with digit > tid
            unsigned needk = (unsigned)(HC_K - above);
            if (suf < needk && suf + cnt >= needk) {
                s_d = tid;
                s_above = above + (int)suf;
            }
        }
        __syncthreads();
        prefix |= ((unsigned)s_d) << s;
        above = s_above;
        __syncthreads();
    }

    unsigned T = prefix;
    int need2 = HC_K - above;  // ties to take, lowest index first

    // mark selected rows in bitS: strictly-above + lowest-index ties
#pragma unroll
    for (int j = 0; j < 14; ++j) {
        unsigned u = key[j];
        int i = j * 1024 + tid;
        if (u > T) atomicOr(&bitS[i >> 5], 1u << (i & 31));
        else if (u == T) {
            int pp = atomicAdd(&s_tie_cnt, 1);
            if (pp < 2048) tie_idx[pp] = i;
        }
    }
    __syncthreads();
    int C = s_tie_cnt;
    if (C <= 2048) {
        for (int m = tid; m < C; m += 1024) {
            int my = tie_idx[m];
            int rank = 0;
            for (int j = 0; j < C; ++j) rank += (tie_idx[j] < my) ? 1 : 0;
            if (rank < need2) atomicOr(&bitS[my >> 5], 1u << (my & 31));
        }
    } else if (tid == 0) {  // degenerate mass-tie fallback (never expected)
        int left = need2;
        for (int i = 0; i < I_DIM && left > 0; ++i)
            if (sortable(h[i]) == T) { atomicOr(&bitS[i >> 5], 1u << (i & 31)); --left; }
    }
    __syncthreads();

    // emit: zero tv for untouched rows; residual list = selected && !topk
#pragma unroll
    for (int j = 0; j < 14; ++j) {
        int i = j * 1024 + tid;
        bool t = (bitT[i >> 5] >> (i & 31)) & 1u;
        bool sl = (bitS[i >> 5] >> (i & 31)) & 1u;
        if (!t) {
            if (sl) {
                int pp = atomicAdd(&s_rc, 1);
                rlist[pp] = i;
            } else {
                tv[i] = 0.f;
            }
        }
    }
    __syncthreads();
    if (tid == 0) *rcount = s_rc;
}

// K3: residual gate/up rows from compact list (<=716 entries).
__global__ __launch_bounds__(256) void k3_residual(
    const float* __restrict__ x, const float* __restrict__ gate_w,
    const float* __restrict__ up_w, const int* __restrict__ rlist,
    const int* __restrict__ rcount, float* __restrict__ tv) {
    int wid = threadIdx.x >> 6, lane = threadIdx.x & 63;
    int gw = blockIdx.x * 4 + wid;
    if (gw < *rcount) compute_tv_row(x, gate_w, up_w, tv, rlist[gw], lane);
}

// K4: out = down_w @ tv (wave per output row, dense over I, nt weight stream).
__global__ __launch_bounds__(256) void k4_down(
    const float* __restrict__ tv, const float* __restrict__ down_w,
    float* __restrict__ out) {
    int wid = threadIdx.x >> 6, lane = threadIdx.x & 63;
    int row = blockIdx.x * 4 + wid;  // 0..4095
    const float* mr = down_w + (size_t)row * I_DIM;
    float s = 0.f;
#pragma unroll 4
    for (int c = 0; c < I_DIM; c += 256) {
        int cc = c + lane * 4;
        floatx4 m = ntload4(mr + cc);
        float4 v = *(const float4*)(tv + cc);
        s += m.x * v.x + m.y * v.y + m.z * v.z + m.w * v.w;
    }
#pragma unroll
    for (int o = 32; o >= 1; o >>= 1) s += __shfl_xor(s, o);
    if (lane == 0) out[row] = s;
}

extern "C" void kernel_launch(void* const* d_in, const int* in_sizes, int n_in,
                              void* d_out, int out_size, void* d_ws, size_t ws_size,
                              hipStream_t stream) {
    const float* x      = (const float*)d_in[0];
    const int*   x_topk = (const int*)d_in[1];
    const float* gate_w = (const float*)d_in[2];
    const float* up_w   = (const float*)d_in[3];
    const float* down_w = (const float*)d_in[4];
    const float* hw1    = (const float*)d_in[5];
    const float* hw2    = (const float*)d_in[6];
    float* out = (float*)d_out;

    float* ws    = (float*)d_ws;
    float* h1    = ws;                             // 1024
    float* hbuf  = ws + 1024;                      // 14336
    float* tv    = ws + 1024 + I_DIM;              // 14336
    int*   rlist = (int*)(ws + 1024 + 2 * I_DIM);  // 716 (+pad)
    int*   rcount = rlist + 768;                   // 1

    // K1: h1 GEMV (256 blocks) || gate/up for all x_topk entries (1075 blocks)
    k1_h1_gateup<<<256 + (SC_K + 3) / 4, 256, 0, stream>>>(x, hw1, x_topk, gate_w,
                                                           up_w, h1, tv);
    // K2: h GEMV
    k2_h<<<I_DIM / 4, 256, 0, stream>>>(h1, hw2, hbuf);
    // K2b: top-716 select -> tv zeros + residual list (single block)
    select_kernel<<<1, 1024, 0, stream>>>(hbuf, x_topk, tv, rlist, rcount);
    // K3: residual gate/up rows (list-driven, 179 blocks)
    k3_residual<<<(HC_K + 3) / 4, 256, 0, stream>>>(x, gate_w, up_w, rlist, rcount, tv);
    // K4: dense down-projection
    k4_down<<<H_DIM / 4, 256, 0, stream>>>(tv, down_w, out);
}